// Round 2
// baseline (2061.986 us; speedup 1.0000x reference)
//
#include <hip/hip_runtime.h>

// ChebNet K=3: x(N,1) -> 32 -> 32 -> 1 over a 2M-edge graph.
// norm[e] = -rsqrt(deg[src]) * rsqrt(deg[dst]),  deg = out-degree (segment over src).
// propagate: y[dst] += norm[e] * x[src].

__global__ void k_deg(const int* __restrict__ src, float* __restrict__ deg, int E) {
    int e = blockIdx.x * blockDim.x + threadIdx.x;
    if (e < E) atomicAdd(&deg[src[e]], 1.0f);
}

__global__ void k_dinv(float* __restrict__ deg, int n) {
    int i = blockIdx.x * blockDim.x + threadIdx.x;
    if (i < n) {
        float d = deg[i];
        deg[i] = (d > 0.0f) ? rsqrtf(fmaxf(d, 1.0f)) : 0.0f;
    }
}

// norm[e] + first scalar propagate fused (layer-1 features are 1-dim)
__global__ void k_norm_prop1(const int* __restrict__ src, const int* __restrict__ dst,
                             const float* __restrict__ dinv, const float* __restrict__ x,
                             float* __restrict__ nrm, float* __restrict__ tx1, int E) {
    int e = blockIdx.x * blockDim.x + threadIdx.x;
    if (e < E) {
        int s = src[e], d = dst[e];
        float nm = -dinv[s] * dinv[d];
        nrm[e] = nm;
        atomicAdd(&tx1[d], nm * x[s]);
    }
}

__global__ void k_prop_scalar(const int* __restrict__ src, const int* __restrict__ dst,
                              const float* __restrict__ nrm, const float* __restrict__ in,
                              float* __restrict__ out, int E) {
    int e = blockIdx.x * blockDim.x + threadIdx.x;
    if (e < E) {
        atomicAdd(&out[dst[e]], nrm[e] * in[src[e]]);
    }
}

// h[i][f] = relu(x[i]*W1[0,0,f] + Tx1[i]*W1[1,0,f] + (2*P2[i]-x[i])*W1[2,0,f] + b1[f])
__global__ void k_layer1(const float* __restrict__ x, const float* __restrict__ tx1,
                         const float* __restrict__ p2, const float* __restrict__ W1,
                         const float* __restrict__ b1, float* __restrict__ h, int n) {
    int idx = blockIdx.x * blockDim.x + threadIdx.x;
    if (idx < n * 32) {
        int i = idx >> 5, f = idx & 31;
        float x0 = x[i];
        float t1 = tx1[i];
        float t2 = 2.0f * p2[i] - x0;
        float v = x0 * W1[f] + t1 * W1[32 + f] + t2 * W1[64 + f] + b1[f];
        h[idx] = fmaxf(v, 0.0f);
    }
}

// 32-dim propagate: 8 threads per edge, float4 per thread (one 128B segment per edge)
__global__ void k_prop_vec(const int* __restrict__ src, const int* __restrict__ dst,
                           const float* __restrict__ nrm, const float* __restrict__ in,
                           float* __restrict__ out, int E) {
    int t = blockIdx.x * blockDim.x + threadIdx.x;
    int e = t >> 3;
    if (e < E) {
        int sub = (t & 7) << 2;
        int s = src[e], d = dst[e];
        float nm = nrm[e];
        float4 v = *reinterpret_cast<const float4*>(in + s * 32 + sub);
        float* o = out + d * 32 + sub;
        atomicAdd(o + 0, nm * v.x);
        atomicAdd(o + 1, nm * v.y);
        atomicAdd(o + 2, nm * v.z);
        atomicAdd(o + 3, nm * v.w);
    }
}

// h2 = relu(h@W2[0] + S1@W2[1] + (2*S1p - h)@W2[2] + b2);  out = h2 @ Wfc + bfc
// Block = 256 threads = 8 nodes x 32 out-features. W2 staged in LDS (12 KB).
__global__ void k_layer2_fc(const float* __restrict__ h, const float* __restrict__ s1,
                            const float* __restrict__ s1p, const float* __restrict__ W2,
                            const float* __restrict__ b2, const float* __restrict__ Wfc,
                            const float* __restrict__ bfc, float* __restrict__ out, int n) {
    __shared__ float W2s[3 * 32 * 32];
    int tid = threadIdx.x;
    for (int j = tid; j < 3 * 32 * 32; j += 256) W2s[j] = W2[j];
    __syncthreads();
    int f = tid & 31;
    int i = blockIdx.x * 8 + (tid >> 5);
    float acc = 0.0f;
    if (i < n) {
        acc = b2[f];
        const float* hr = h   + (size_t)i * 32;
        const float* ar = s1  + (size_t)i * 32;
        const float* br = s1p + (size_t)i * 32;
        #pragma unroll
        for (int k = 0; k < 32; ++k) {
            float hk  = hr[k];
            float s1k = ar[k];
            float s2k = 2.0f * br[k] - hk;
            acc += hk * W2s[k * 32 + f] + s1k * W2s[1024 + k * 32 + f] + s2k * W2s[2048 + k * 32 + f];
        }
        acc = fmaxf(acc, 0.0f) * Wfc[f];
    }
    #pragma unroll
    for (int m = 16; m >= 1; m >>= 1) acc += __shfl_xor(acc, m, 32);
    if (i < n && f == 0) out[i] = acc + bfc[0];
}

extern "C" void kernel_launch(void* const* d_in, const int* in_sizes, int n_in,
                              void* d_out, int out_size, void* d_ws, size_t ws_size,
                              hipStream_t stream) {
    const float* x   = (const float*)d_in[0];
    const int*   ei  = (const int*)d_in[1];
    const float* W1  = (const float*)d_in[2];
    const float* b1  = (const float*)d_in[3];
    const float* W2  = (const float*)d_in[4];
    const float* b2  = (const float*)d_in[5];
    const float* Wfc = (const float*)d_in[6];
    const float* bfc = (const float*)d_in[7];
    float* out = (float*)d_out;

    const int n = in_sizes[0];       // N (x is N x 1)
    const int E = in_sizes[1] / 2;   // edge_index is (2, E)
    const int* src = ei;
    const int* dst = ei + E;

    // workspace layout (floats):
    // [deg n][tx1 n][p2 n][s1 32n][s1p 32n]  <-- contiguous accumulators, zeroed
    // [nrm E][h 32n]                          <-- fully overwritten, no zeroing
    float* ws  = (float*)d_ws;
    float* deg = ws;
    float* tx1 = deg + n;
    float* p2  = tx1 + n;
    float* s1  = p2 + n;
    float* s1p = s1 + (size_t)32 * n;
    float* nrm = s1p + (size_t)32 * n;
    float* h   = nrm + E;

    size_t zeroBytes = (size_t)(3 + 64) * n * sizeof(float);
    hipMemsetAsync(d_ws, 0, zeroBytes, stream);

    const int B = 256;
    k_deg<<<(E + B - 1) / B, B, 0, stream>>>(src, deg, E);
    k_dinv<<<(n + B - 1) / B, B, 0, stream>>>(deg, n);
    k_norm_prop1<<<(E + B - 1) / B, B, 0, stream>>>(src, dst, deg, x, nrm, tx1, E);
    k_prop_scalar<<<(E + B - 1) / B, B, 0, stream>>>(src, dst, nrm, tx1, p2, E);
    k_layer1<<<(n * 32 + B - 1) / B, B, 0, stream>>>(x, tx1, p2, W1, b1, h, n);
    k_prop_vec<<<(E * 8 + B - 1) / B, B, 0, stream>>>(src, dst, nrm, h, s1, E);
    k_prop_vec<<<(E * 8 + B - 1) / B, B, 0, stream>>>(src, dst, nrm, s1, s1p, E);
    k_layer2_fc<<<(n + 7) / 8, B, 0, stream>>>(h, s1, s1p, W2, b2, Wfc, bfc, out, n);
}

// Round 3
// 605.339 us; speedup vs baseline: 3.4063x; 3.4063x over previous
//
#include <hip/hip_runtime.h>

// ChebNet K=3 via device-built CSR (by dst) + gather-side propagates (no scatter atomics).
// norm[e] = -rsqrt(deg_src[src]) * rsqrt(deg_src[dst]) baked into CSR values.
// propagate: y[i] = sum_{e: dst=i} val[e] * x[col[e]]

#define BS 256

// Histogram both endpoints: degs = degree over src (for norm), cnt = in-degree over dst (for CSR).
__global__ void k_hist(const int* __restrict__ src, const int* __restrict__ dst,
                       int* __restrict__ degs, int* __restrict__ cnt, int E) {
    int e = blockIdx.x * BS + threadIdx.x;
    if (e < E) {
        atomicAdd(&degs[src[e]], 1);
        atomicAdd(&cnt[dst[e]], 1);
    }
}

__global__ void k_dinv(const int* __restrict__ degs, float* __restrict__ dinv, int n) {
    int i = blockIdx.x * BS + threadIdx.x;
    if (i < n) {
        float d = (float)degs[i];
        dinv[i] = (d > 0.0f) ? rsqrtf(fmaxf(d, 1.0f)) : 0.0f;
    }
}

// --- 3-kernel exclusive scan of cnt[0..n) into rowptr[0..n], rowptr[n]=E ---
__global__ void k_scanA(const int* __restrict__ cnt, int* __restrict__ rowptr,
                        int* __restrict__ part, int n) {
    __shared__ int sh[BS];
    int t = threadIdx.x, i = blockIdx.x * BS + t;
    int v = (i < n) ? cnt[i] : 0;
    sh[t] = v; __syncthreads();
    int acc = v;
    for (int d = 1; d < BS; d <<= 1) {
        int add = (t >= d) ? sh[t - d] : 0;
        __syncthreads();
        acc += add; sh[t] = acc;
        __syncthreads();
    }
    if (i < n) rowptr[i] = acc - v;              // exclusive within block
    if (t == BS - 1) part[blockIdx.x] = acc;     // block total
}

__global__ void k_scanB(int* __restrict__ part, int nb) {  // nb <= 512
    __shared__ int sh[512];
    int t = threadIdx.x;
    int v = (t < nb) ? part[t] : 0;
    sh[t] = v; __syncthreads();
    int acc = v;
    for (int d = 1; d < 512; d <<= 1) {
        int add = (t >= d) ? sh[t - d] : 0;
        __syncthreads();
        acc += add; sh[t] = acc;
        __syncthreads();
    }
    if (t < nb) part[t] = acc - v;               // exclusive
}

__global__ void k_scanC(int* __restrict__ rowptr, int* __restrict__ cursor,
                        const int* __restrict__ part, int n, int E) {
    int i = blockIdx.x * BS + threadIdx.x;
    if (i < n) {
        int r = rowptr[i] + part[i >> 8];
        rowptr[i] = r;
        cursor[i] = r;
    }
    if (i == n) rowptr[n] = E;
}

// Counting-sort fill: CSR (col=src, val=norm) grouped by dst. Order within a row is arbitrary.
__global__ void k_build(const int* __restrict__ src, const int* __restrict__ dst,
                        const float* __restrict__ dinv, int* __restrict__ cursor,
                        int* __restrict__ colv, float* __restrict__ valv, int E) {
    int e = blockIdx.x * BS + threadIdx.x;
    if (e < E) {
        int s = src[e], d = dst[e];
        float nm = -dinv[s] * dinv[d];
        int pos = atomicAdd(&cursor[d], 1);
        colv[pos] = s;
        valv[pos] = nm;
    }
}

// Scalar propagate: 1 thread per node.
__global__ void k_prop_s_csr(const int* __restrict__ rowptr, const int* __restrict__ colv,
                             const float* __restrict__ valv, const float* __restrict__ in,
                             float* __restrict__ out, int n) {
    int i = blockIdx.x * BS + threadIdx.x;
    if (i < n) {
        int b = rowptr[i], e = rowptr[i + 1];
        float s = 0.0f;
        for (int j = b; j < e; ++j) s += valv[j] * in[colv[j]];
        out[i] = s;
    }
}

// 32-dim propagate: 8 lanes per node, each lane owns one float4 (features ln*4..ln*4+3).
// Per edge: one 128B coalesced gather across the 8-lane group; col/val broadcast.
__global__ void k_prop_v_csr(const int* __restrict__ rowptr, const int* __restrict__ colv,
                             const float* __restrict__ valv, const float* __restrict__ in,
                             float* __restrict__ out, int n) {
    int t = blockIdx.x * BS + threadIdx.x;
    int node = t >> 3;
    if (node < n) {
        int ln4 = (t & 7) << 2;
        int b = rowptr[node], e = rowptr[node + 1];
        float4 acc = make_float4(0.f, 0.f, 0.f, 0.f);
        for (int j = b; j < e; ++j) {
            int s = colv[j];
            float nm = valv[j];
            float4 v = *reinterpret_cast<const float4*>(in + s * 32 + ln4);
            acc.x += nm * v.x; acc.y += nm * v.y; acc.z += nm * v.z; acc.w += nm * v.w;
        }
        *reinterpret_cast<float4*>(out + node * 32 + ln4) = acc;
    }
}

// h[i][f] = relu(x[i]*W1[0,0,f] + tx1[i]*W1[1,0,f] + (2*p2[i]-x[i])*W1[2,0,f] + b1[f])
__global__ void k_layer1(const float* __restrict__ x, const float* __restrict__ tx1,
                         const float* __restrict__ p2, const float* __restrict__ W1,
                         const float* __restrict__ b1, float* __restrict__ h, int n) {
    int idx = blockIdx.x * BS + threadIdx.x;
    if (idx < n * 32) {
        int i = idx >> 5, f = idx & 31;
        float x0 = x[i];
        float t1 = tx1[i];
        float t2 = 2.0f * p2[i] - x0;
        float v = x0 * W1[f] + t1 * W1[32 + f] + t2 * W1[64 + f] + b1[f];
        h[idx] = fmaxf(v, 0.0f);
    }
}

// h2 = relu(h@W2[0] + s1@W2[1] + (2*s1p - h)@W2[2] + b2);  out = h2 @ Wfc + bfc
__global__ void k_layer2_fc(const float* __restrict__ h, const float* __restrict__ s1,
                            const float* __restrict__ s1p, const float* __restrict__ W2,
                            const float* __restrict__ b2, const float* __restrict__ Wfc,
                            const float* __restrict__ bfc, float* __restrict__ out, int n) {
    __shared__ float W2s[3 * 32 * 32];
    int tid = threadIdx.x;
    for (int j = tid; j < 3 * 32 * 32; j += BS) W2s[j] = W2[j];
    __syncthreads();
    int f = tid & 31;
    int i = blockIdx.x * 8 + (tid >> 5);
    float acc = 0.0f;
    if (i < n) {
        acc = b2[f];
        const float* hr = h   + (size_t)i * 32;
        const float* ar = s1  + (size_t)i * 32;
        const float* br = s1p + (size_t)i * 32;
        #pragma unroll
        for (int k = 0; k < 32; ++k) {
            float hk  = hr[k];
            float s1k = ar[k];
            float s2k = 2.0f * br[k] - hk;
            acc += hk * W2s[k * 32 + f] + s1k * W2s[1024 + k * 32 + f] + s2k * W2s[2048 + k * 32 + f];
        }
        acc = fmaxf(acc, 0.0f) * Wfc[f];
    }
    #pragma unroll
    for (int m = 16; m >= 1; m >>= 1) acc += __shfl_xor(acc, m, 32);
    if (i < n && f == 0) out[i] = acc + bfc[0];
}

extern "C" void kernel_launch(void* const* d_in, const int* in_sizes, int n_in,
                              void* d_out, int out_size, void* d_ws, size_t ws_size,
                              hipStream_t stream) {
    const float* x   = (const float*)d_in[0];
    const int*   ei  = (const int*)d_in[1];
    const float* W1  = (const float*)d_in[2];
    const float* b1  = (const float*)d_in[3];
    const float* W2  = (const float*)d_in[4];
    const float* b2  = (const float*)d_in[5];
    const float* Wfc = (const float*)d_in[6];
    const float* bfc = (const float*)d_in[7];
    float* out = (float*)d_out;

    const int n = in_sizes[0];       // N
    const int E = in_sizes[1] / 2;   // edge_index (2,E)
    const int* src = ei;
    const int* dst = ei + E;
    const int NB = (n + BS - 1) / BS;        // scan blocks (must be <= 512)

    // workspace layout (4B words; all regions 16B-aligned: n % 4 == 0, rowptr padded)
    int*   cnt    = (int*)d_ws;              // n   (zeroed)
    int*   degs   = cnt + n;                 // n   (zeroed)
    int*   rowptr = degs + n;                // n+4
    int*   cursor = rowptr + n + 4;          // n
    int*   part   = cursor + n;              // 512
    float* dinv   = (float*)(part + 512);    // n
    int*   colv   = (int*)(dinv + n);        // E
    float* valv   = (float*)(colv + E);      // E
    float* tx1    = valv + E;                // n
    float* p2     = tx1 + n;                 // n
    float* h      = p2 + n;                  // 32n
    float* s1     = h + (size_t)32 * n;      // 32n
    float* s1p    = s1 + (size_t)32 * n;     // 32n

    hipMemsetAsync(d_ws, 0, (size_t)2 * n * sizeof(int), stream);

    const int EB = (E + BS - 1) / BS;
    k_hist <<<EB, BS, 0, stream>>>(src, dst, degs, cnt, E);
    k_dinv <<<NB, BS, 0, stream>>>(degs, dinv, n);
    k_scanA<<<NB, BS, 0, stream>>>(cnt, rowptr, part, n);
    k_scanB<<<1, 512, 0, stream>>>(part, NB);
    k_scanC<<<NB, BS, 0, stream>>>(rowptr, cursor, part, n, E);
    k_build<<<EB, BS, 0, stream>>>(src, dst, dinv, cursor, colv, valv, E);

    // Layer 1 (scalar features)
    k_prop_s_csr<<<NB, BS, 0, stream>>>(rowptr, colv, valv, x, tx1, n);
    k_prop_s_csr<<<NB, BS, 0, stream>>>(rowptr, colv, valv, tx1, p2, n);
    k_layer1<<<(n * 32 + BS - 1) / BS, BS, 0, stream>>>(x, tx1, p2, W1, b1, h, n);

    // Layer 2 (32-dim features)
    k_prop_v_csr<<<(n * 8 + BS - 1) / BS, BS, 0, stream>>>(rowptr, colv, valv, h, s1, n);
    k_prop_v_csr<<<(n * 8 + BS - 1) / BS, BS, 0, stream>>>(rowptr, colv, valv, s1, s1p, n);
    k_layer2_fc<<<(n + 7) / 8, BS, 0, stream>>>(h, s1, s1p, W2, b2, Wfc, bfc, out, n);
}